// Round 1
// baseline (461.549 us; speedup 1.0000x reference)
//
#include <hip/hip_runtime.h>
#include <stdint.h>

#define D_EMB 1024
#define NBATCH 8
#define SEQ 2048
#define MTOT (NBATCH*SEQ)   // 16384

typedef __attribute__((ext_vector_type(8))) short short8;
typedef __attribute__((ext_vector_type(4))) float f32x4;

__device__ __forceinline__ ushort bf16r(float x) {
  union { float f; uint32_t u; } c; c.f = x;
  return (ushort)((c.u + 0x7fffu + ((c.u >> 16) & 1u)) >> 16);
}

// ---------------- f32 -> bf16 convert (x4 vectorized) ----------------
__global__ void cvt_kernel(const float4* __restrict__ in, ushort* __restrict__ out, long n4) {
  long i = blockIdx.x * (long)blockDim.x + threadIdx.x;
  long stride = (long)gridDim.x * blockDim.x;
  for (; i < n4; i += stride) {
    float4 v = in[i];
    ushort4 o = make_ushort4(bf16r(v.x), bf16r(v.y), bf16r(v.z), bf16r(v.w));
    *(ushort4*)(out + i * 4) = o;
  }
}

__device__ __forceinline__ float block_reduce_sum_256(float v) {
  __shared__ float red[4];
  int lane = threadIdx.x & 63, wave = threadIdx.x >> 6;
  #pragma unroll
  for (int off = 32; off; off >>= 1) v += __shfl_xor(v, off);
  if (lane == 0) red[wave] = v;
  __syncthreads();
  return red[0] + red[1] + red[2] + red[3];
}

// w_eff[c] = sum_d Wfc[d]*Wp[d,c] ; sc[0] = c_eff = sum_d bp[d]*Wfc[d] + bfc
__global__ void prep1(const float* __restrict__ Wp, const float* __restrict__ Wfc,
                      const float* __restrict__ bp, const float* __restrict__ bfc,
                      float* __restrict__ w_eff, float* __restrict__ sc) {
  if (blockIdx.x < 4) {
    int c = blockIdx.x * 256 + threadIdx.x;
    float s = 0.f;
    for (int d = 0; d < D_EMB; d++) s += Wfc[d] * Wp[d * D_EMB + c];
    w_eff[c] = s;
  } else {
    float s = 0.f;
    #pragma unroll
    for (int i = 0; i < 4; i++) { int d = threadIdx.x + i * 256; s += bp[d] * Wfc[d]; }
    float tot = block_reduce_sum_256(s);
    if (threadIdx.x == 0) sc[0] = tot + bfc[0];
  }
}

// wv_eff[d] = sum_c w_eff[c]*Wattn[2048+c, d] ; sc[1] = vb_eff = sum_c battn[2048+c]*w_eff[c]
__global__ void prep2(const float* __restrict__ Wattn, const float* __restrict__ battn,
                      const float* __restrict__ w_eff, float* __restrict__ wv_eff,
                      float* __restrict__ sc) {
  if (blockIdx.x < 4) {
    int d = blockIdx.x * 256 + threadIdx.x;
    float s = 0.f;
    for (int c = 0; c < D_EMB; c++) s += w_eff[c] * Wattn[(long)(2048 + c) * D_EMB + d];
    wv_eff[d] = s;
  } else {
    float s = 0.f;
    #pragma unroll
    for (int i = 0; i < 4; i++) { int c = threadIdx.x + i * 256; s += battn[2048 + c] * w_eff[c]; }
    float tot = block_reduce_sum_256(s);
    if (threadIdx.x == 0) sc[1] = tot;
  }
}

// vw[m] = x[m,:] . wv_eff + vb_eff   (one wave per row, fp32)
__global__ void vw_kernel(const float* __restrict__ x, const float* __restrict__ wv_eff,
                          const float* __restrict__ sc, float* __restrict__ vw) {
  int wave = threadIdx.x >> 6, lane = threadIdx.x & 63;
  long m = (long)blockIdx.x * 4 + wave;
  const float* xr = x + m * D_EMB;
  float s = 0.f;
  #pragma unroll
  for (int i = 0; i < 16; i++) s += xr[i * 64 + lane] * wv_eff[i * 64 + lane];
  #pragma unroll
  for (int off = 32; off; off >>= 1) s += __shfl_xor(s, off);
  if (lane == 0) vw[m] = s + sc[1];
}

// ---------------- NT GEMM: C[m,n] = scale * sum_k A[m,k]*B[n,k] (+bias[n]) ----------------
// 128x128 tile, BK=32, 4 waves, each wave 64x64 (4x4 frags of 16x16x32 bf16 MFMA)
template<bool OUT_BF16>
__global__ __launch_bounds__(256) void gemm_nt(
    const ushort* __restrict__ A, long lda, long sAz,
    const ushort* __restrict__ B, long ldb, long sBz,
    void* __restrict__ Cv, long ldc, long sCz,
    const float* __restrict__ bias, float scale, int K) {
  __shared__ __align__(16) ushort lds_a[128 * 32];
  __shared__ __align__(16) ushort lds_b[128 * 32];
  int z = blockIdx.z;
  const ushort* Az = A + (long)z * sAz;
  const ushort* Bz = B + (long)z * sBz;
  long m0 = (long)blockIdx.y * 128, n0 = (long)blockIdx.x * 128;
  int t = threadIdx.x;
  int wave = t >> 6, lane = t & 63;
  int r = lane & 15, q = lane >> 4;
  int wm = (wave & 1) * 64, wn = (wave >> 1) * 64;

  f32x4 acc[4][4] = {};

  // staging: slot s = row*4 + kchunk (row-major, 16B/slot); thread handles slots t, t+256
  int row0 = t >> 2, kc = t & 3;
  const ushort* Ap0 = Az + (m0 + row0) * lda + kc * 8;
  const ushort* Ap1 = Az + (m0 + row0 + 64) * lda + kc * 8;
  const ushort* Bp0 = Bz + (n0 + row0) * ldb + kc * 8;
  const ushort* Bp1 = Bz + (n0 + row0 + 64) * ldb + kc * 8;

  #pragma unroll 1
  for (int k0 = 0; k0 < K; k0 += 32) {
    uint4 a0 = *(const uint4*)(Ap0 + k0);
    uint4 a1 = *(const uint4*)(Ap1 + k0);
    uint4 b0 = *(const uint4*)(Bp0 + k0);
    uint4 b1 = *(const uint4*)(Bp1 + k0);
    if (k0) __syncthreads();
    *(uint4*)(lds_a + t * 8) = a0;
    *(uint4*)(lds_a + (t + 256) * 8) = a1;
    *(uint4*)(lds_b + t * 8) = b0;
    *(uint4*)(lds_b + (t + 256) * 8) = b1;
    __syncthreads();
    short8 af[4], bf[4];
    #pragma unroll
    for (int i = 0; i < 4; i++)
      af[i] = *(const short8*)(lds_a + ((wm + i * 16 + r) * 4 + q) * 8);
    #pragma unroll
    for (int j = 0; j < 4; j++)
      bf[j] = *(const short8*)(lds_b + ((wn + j * 16 + r) * 4 + q) * 8);
    #pragma unroll
    for (int i = 0; i < 4; i++)
      #pragma unroll
      for (int j = 0; j < 4; j++)
        acc[i][j] = __builtin_amdgcn_mfma_f32_16x16x32_bf16(af[i], bf[j], acc[i][j], 0, 0, 0);
  }

  // epilogue: D row = wm+i*16+q*4+rr, col = wn+j*16+r  (verified C/D layout)
  #pragma unroll
  for (int i = 0; i < 4; i++) {
    #pragma unroll
    for (int j = 0; j < 4; j++) {
      long col = n0 + wn + j * 16 + r;
      float bj = (OUT_BF16 && bias) ? bias[col] : 0.f;
      #pragma unroll
      for (int rr = 0; rr < 4; rr++) {
        long row = m0 + wm + i * 16 + q * 4 + rr;
        float val = acc[i][j][rr] * scale + bj;
        if (OUT_BF16) ((ushort*)Cv)[(long)z * sCz + row * ldc + col] = bf16r(val);
        else          ((float*)Cv)[(long)z * sCz + row * ldc + col] = val;
      }
    }
  }
}

// softmax over s of scores[row, :] then dot with vw[b, :]; out = dot/sum + c_eff
__global__ __launch_bounds__(256) void softmax_out(
    const float* __restrict__ scores, const float* __restrict__ vw,
    const float* __restrict__ sc, float* __restrict__ out) {
  long row = blockIdx.x;
  int b = (int)(row >> 11);
  const float* srow = scores + row * SEQ;
  const float* vwr = vw + ((long)b << 11);
  int tid = threadIdx.x;
  int wave = tid >> 6, lane = tid & 63;
  float vals[8];
  float mx = -1e30f;
  #pragma unroll
  for (int i = 0; i < 8; i++) { vals[i] = srow[tid + i * 256]; mx = fmaxf(mx, vals[i]); }
  #pragma unroll
  for (int off = 32; off; off >>= 1) mx = fmaxf(mx, __shfl_xor(mx, off));
  __shared__ float wmax[4];
  if (lane == 0) wmax[wave] = mx;
  __syncthreads();
  mx = fmaxf(fmaxf(wmax[0], wmax[1]), fmaxf(wmax[2], wmax[3]));
  float se = 0.f, sd = 0.f;
  #pragma unroll
  for (int i = 0; i < 8; i++) {
    float e = __expf(vals[i] - mx);
    se += e;
    sd += e * vwr[tid + i * 256];
  }
  #pragma unroll
  for (int off = 32; off; off >>= 1) { se += __shfl_xor(se, off); sd += __shfl_xor(sd, off); }
  __shared__ float wse[4], wsd[4];
  if (lane == 0) { wse[wave] = se; wsd[wave] = sd; }
  __syncthreads();
  if (tid == 0) {
    float S = wse[0] + wse[1] + wse[2] + wse[3];
    float Dd = wsd[0] + wsd[1] + wsd[2] + wsd[3];
    out[row] = Dd / S + sc[0];
  }
}

extern "C" void kernel_launch(void* const* d_in, const int* in_sizes, int n_in,
                              void* d_out, int out_size, void* d_ws, size_t ws_size,
                              hipStream_t stream) {
  const float* x     = (const float*)d_in[0];
  const float* Wattn = (const float*)d_in[1];
  const float* battn = (const float*)d_in[2];
  const float* Wproj = (const float*)d_in[3];
  const float* bproj = (const float*)d_in[4];
  const float* Wfc   = (const float*)d_in[5];
  const float* bfc   = (const float*)d_in[6];
  float* out = (float*)d_out;

  // ws layout (bytes)
  const size_t OFF_XB     = 0;                         // bf16 [16384][1024]  33554432
  const size_t OFF_WQKB   = 33554432;                  // bf16 [2048][1024]    4194304
  const size_t OFF_QK     = 37748736;                  // bf16 [16384][2048]  67108864
  const size_t OFF_SCORES = 104857600;                 // f32  [8][2048][2048] 134217728
  const size_t OFF_VW     = 239075328;                 // f32  [16384]           65536
  const size_t OFF_WEFF   = 239140864;                 // f32  [1024]
  const size_t OFF_WVEFF  = 239144960;                 // f32  [1024]
  const size_t OFF_SC     = 239149056;                 // f32  [2] {c_eff, vb_eff}
  const size_t NEED       = 239149064;
  if (ws_size < NEED) return;  // clean fail -> signals ws too small

  char* ws = (char*)d_ws;
  ushort* xb    = (ushort*)(ws + OFF_XB);
  ushort* wqkb  = (ushort*)(ws + OFF_WQKB);
  ushort* qk    = (ushort*)(ws + OFF_QK);
  float* scores = (float*)(ws + OFF_SCORES);
  float* vw     = (float*)(ws + OFF_VW);
  float* w_eff  = (float*)(ws + OFF_WEFF);
  float* wv_eff = (float*)(ws + OFF_WVEFF);
  float* sc     = (float*)(ws + OFF_SC);

  cvt_kernel<<<dim3(4096), dim3(256), 0, stream>>>((const float4*)x, xb, (long)MTOT * D_EMB / 4);
  cvt_kernel<<<dim3(2048), dim3(256), 0, stream>>>((const float4*)Wattn, wqkb, (long)2048 * D_EMB / 4);
  prep1<<<dim3(5), dim3(256), 0, stream>>>(Wproj, Wfc, bproj, bfc, w_eff, sc);
  prep2<<<dim3(5), dim3(256), 0, stream>>>(Wattn, battn, w_eff, wv_eff, sc);
  vw_kernel<<<dim3(4096), dim3(256), 0, stream>>>(x, wv_eff, sc, vw);

  // GEMM1: qk[m, n] = x[m,:] . Wattn[n,:] + battn[n], n in [0,2048)
  gemm_nt<true><<<dim3(16, 128, 1), dim3(256), 0, stream>>>(
      xb, (long)D_EMB, 0L, wqkb, (long)D_EMB, 0L,
      (void*)qk, 2048L, 0L, battn, 1.0f, D_EMB);

  // GEMM2: scores[b, t, s] = (q[b,t,:] . k[b,s,:]) / 32
  gemm_nt<false><<<dim3(16, 16, NBATCH), dim3(256), 0, stream>>>(
      qk, 2048L, (long)SEQ * 2048, qk + 1024, 2048L, (long)SEQ * 2048,
      (void*)scores, (long)SEQ, (long)SEQ * SEQ, nullptr, 0.03125f, D_EMB);

  softmax_out<<<dim3(MTOT), dim3(256), 0, stream>>>(scores, vw, sc, out);
}

// Round 2
// 359.284 us; speedup vs baseline: 1.2846x; 1.2846x over previous
//
#include <hip/hip_runtime.h>
#include <stdint.h>

#define D_EMB 1024
#define NBATCH 8
#define SEQ 2048
#define MTOT (NBATCH*SEQ)   // 16384

typedef __attribute__((ext_vector_type(8))) short short8;
typedef __attribute__((ext_vector_type(4))) float f32x4;

__device__ __forceinline__ ushort bf16r(float x) {
  union { float f; uint32_t u; } c; c.f = x;
  return (ushort)((c.u + 0x7fffu + ((c.u >> 16) & 1u)) >> 16);
}

// async 16B/lane global->LDS (wave-uniform LDS base + lane*16 layout required)
__device__ __forceinline__ void cp16(const ushort* g, ushort* l) {
  __builtin_amdgcn_global_load_lds(
      (const __attribute__((address_space(1))) void*)g,
      (__attribute__((address_space(3))) void*)l, 16, 0, 0);
}

// ---------------- f32 -> bf16 convert (x4 vectorized) ----------------
__global__ void cvt_kernel(const float4* __restrict__ in, ushort* __restrict__ out, long n4) {
  long i = blockIdx.x * (long)blockDim.x + threadIdx.x;
  long stride = (long)gridDim.x * blockDim.x;
  for (; i < n4; i += stride) {
    float4 v = in[i];
    ushort4 o = make_ushort4(bf16r(v.x), bf16r(v.y), bf16r(v.z), bf16r(v.w));
    *(ushort4*)(out + i * 4) = o;
  }
}

// block 0: zero w_eff; block 1: zero wv_eff; block 2: sc[0] = sum_d bp[d]*Wfc[d] + bfc
__global__ void zero_sc0(const float* __restrict__ bp, const float* __restrict__ Wfc,
                         const float* __restrict__ bfc,
                         float* __restrict__ w_eff, float* __restrict__ wv_eff,
                         float* __restrict__ sc) {
  int tid = threadIdx.x;
  if (blockIdx.x == 0) { w_eff[tid] = 0.f; return; }
  if (blockIdx.x == 1) { wv_eff[tid] = 0.f; return; }
  float v = bp[tid] * Wfc[tid];
  int lane = tid & 63, w = tid >> 6;
  #pragma unroll
  for (int off = 32; off; off >>= 1) v += __shfl_xor(v, off);
  __shared__ float red[16];
  if (lane == 0) red[w] = v;
  __syncthreads();
  if (tid == 0) {
    float s = 0.f;
    #pragma unroll
    for (int i = 0; i < 16; i++) s += red[i];
    sc[0] = s + bfc[0];
  }
}

// w_eff[c] += sum over 64-d-chunk of Wfc[d]*Wp[d,c]   grid(4,16)
__global__ void prep1(const float* __restrict__ Wp, const float* __restrict__ Wfc,
                      float* __restrict__ w_eff) {
  int c = blockIdx.x * 256 + threadIdx.x;
  int d0 = blockIdx.y * 64;
  float s = 0.f;
  #pragma unroll 8
  for (int d = d0; d < d0 + 64; d++) s += Wfc[d] * Wp[(long)d * D_EMB + c];
  atomicAdd(&w_eff[c], s);
}

// sc[1] = vb_eff = sum_c battn[2048+c]*w_eff[c]   (after prep1)
__global__ void sc1_kernel(const float* __restrict__ battn, const float* __restrict__ w_eff,
                           float* __restrict__ sc) {
  int tid = threadIdx.x;
  float v = battn[2048 + tid] * w_eff[tid];
  int lane = tid & 63, w = tid >> 6;
  #pragma unroll
  for (int off = 32; off; off >>= 1) v += __shfl_xor(v, off);
  __shared__ float red[16];
  if (lane == 0) red[w] = v;
  __syncthreads();
  if (tid == 0) {
    float s = 0.f;
    #pragma unroll
    for (int i = 0; i < 16; i++) s += red[i];
    sc[1] = s;
  }
}

// wv_eff[d] += sum over 64-c-chunk of w_eff[c]*Wattn[2048+c, d]   grid(4,16)
__global__ void prep2(const float* __restrict__ Wattn, const float* __restrict__ w_eff,
                      float* __restrict__ wv_eff) {
  int d = blockIdx.x * 256 + threadIdx.x;
  int c0 = blockIdx.y * 64;
  float s = 0.f;
  #pragma unroll 8
  for (int c = c0; c < c0 + 64; c++) s += w_eff[c] * Wattn[(long)(2048 + c) * D_EMB + d];
  atomicAdd(&wv_eff[d], s);
}

// vw[m] = x[m,:] . wv_eff + vb_eff   (one wave per row, fp32)
__global__ void vw_kernel(const float* __restrict__ x, const float* __restrict__ wv_eff,
                          const float* __restrict__ sc, float* __restrict__ vw) {
  int wave = threadIdx.x >> 6, lane = threadIdx.x & 63;
  long m = (long)blockIdx.x * 4 + wave;
  const float* xr = x + m * D_EMB;
  float s = 0.f;
  #pragma unroll
  for (int i = 0; i < 16; i++) s += xr[i * 64 + lane] * wv_eff[i * 64 + lane];
  #pragma unroll
  for (int off = 32; off; off >>= 1) s += __shfl_xor(s, off);
  if (lane == 0) vw[m] = s + sc[1];
}

// ---------------- NT GEMM: C[m,n] = scale * sum_k A[m,k]*B[n,k] (+bias[n]) ----------------
// 128x128 tile, BK=32, 4 waves, each wave 64x64 (4x4 frags of 16x16x32 bf16 MFMA)
// staging via global_load_lds width=16 (m97 pattern)
template<bool OUT_BF16>
__global__ __launch_bounds__(256) void gemm_nt(
    const ushort* __restrict__ A, long lda, long sAz,
    const ushort* __restrict__ B, long ldb, long sBz,
    void* __restrict__ Cv, long ldc, long sCz,
    const float* __restrict__ bias, float scale, int K) {
  __shared__ __align__(16) ushort lds_a[128 * 32];
  __shared__ __align__(16) ushort lds_b[128 * 32];
  int z = blockIdx.z;
  const ushort* Az = A + (long)z * sAz;
  const ushort* Bz = B + (long)z * sBz;
  long m0 = (long)blockIdx.y * 128, n0 = (long)blockIdx.x * 128;
  int t = threadIdx.x;
  int wave = t >> 6, lane = t & 63;
  int r = lane & 15, q = lane >> 4;
  int wm = (wave & 1) * 64, wn = (wave >> 1) * 64;

  f32x4 acc[4][4] = {};

  // staging: LDS slot s = row*4 + kchunk (16B/slot); thread t owns slots t and t+256.
  // Within a wave: slot = wave*64 + lane -> LDS addr = wave-uniform base + lane*16. OK for global_load_lds.
  int row0 = t >> 2, kc = t & 3;
  const ushort* Ap0 = Az + (m0 + row0) * lda + kc * 8;
  const ushort* Ap1 = Az + (m0 + row0 + 64) * lda + kc * 8;
  const ushort* Bp0 = Bz + (n0 + row0) * ldb + kc * 8;
  const ushort* Bp1 = Bz + (n0 + row0 + 64) * ldb + kc * 8;

  #pragma unroll 1
  for (int k0 = 0; k0 < K; k0 += 32) {
    if (k0) __syncthreads();
    cp16(Ap0 + k0, lds_a + t * 8);
    cp16(Ap1 + k0, lds_a + (t + 256) * 8);
    cp16(Bp0 + k0, lds_b + t * 8);
    cp16(Bp1 + k0, lds_b + (t + 256) * 8);
    __syncthreads();
    short8 af[4], bf[4];
    #pragma unroll
    for (int i = 0; i < 4; i++)
      af[i] = *(const short8*)(lds_a + ((wm + i * 16 + r) * 4 + q) * 8);
    #pragma unroll
    for (int j = 0; j < 4; j++)
      bf[j] = *(const short8*)(lds_b + ((wn + j * 16 + r) * 4 + q) * 8);
    #pragma unroll
    for (int i = 0; i < 4; i++)
      #pragma unroll
      for (int j = 0; j < 4; j++)
        acc[i][j] = __builtin_amdgcn_mfma_f32_16x16x32_bf16(af[i], bf[j], acc[i][j], 0, 0, 0);
  }

  // epilogue: D row = wm+i*16+q*4+rr, col = wn+j*16+r  (verified C/D layout)
  #pragma unroll
  for (int i = 0; i < 4; i++) {
    #pragma unroll
    for (int j = 0; j < 4; j++) {
      long col = n0 + wn + j * 16 + r;
      float bj = (OUT_BF16 && bias) ? bias[col] : 0.f;
      #pragma unroll
      for (int rr = 0; rr < 4; rr++) {
        long row = m0 + wm + i * 16 + q * 4 + rr;
        float val = acc[i][j][rr] * scale + bj;
        if (OUT_BF16) ((ushort*)Cv)[(long)z * sCz + row * ldc + col] = bf16r(val);
        else          ((float*)Cv)[(long)z * sCz + row * ldc + col] = val;
      }
    }
  }
}

// softmax over s of scores[row, :] then dot with vw[b, :]; out = dot/sum + c_eff
__global__ __launch_bounds__(256) void softmax_out(
    const float* __restrict__ scores, const float* __restrict__ vw,
    const float* __restrict__ sc, float* __restrict__ out) {
  long row = blockIdx.x;
  int b = (int)(row >> 11);
  const float* srow = scores + row * SEQ;
  const float* vwr = vw + ((long)b << 11);
  int tid = threadIdx.x;
  int wave = tid >> 6, lane = tid & 63;
  float vals[8];
  float mx = -1e30f;
  #pragma unroll
  for (int i = 0; i < 8; i++) { vals[i] = srow[tid + i * 256]; mx = fmaxf(mx, vals[i]); }
  #pragma unroll
  for (int off = 32; off; off >>= 1) mx = fmaxf(mx, __shfl_xor(mx, off));
  __shared__ float wmax[4];
  if (lane == 0) wmax[wave] = mx;
  __syncthreads();
  mx = fmaxf(fmaxf(wmax[0], wmax[1]), fmaxf(wmax[2], wmax[3]));
  float se = 0.f, sd = 0.f;
  #pragma unroll
  for (int i = 0; i < 8; i++) {
    float e = __expf(vals[i] - mx);
    se += e;
    sd += e * vwr[tid + i * 256];
  }
  #pragma unroll
  for (int off = 32; off; off >>= 1) { se += __shfl_xor(se, off); sd += __shfl_xor(sd, off); }
  __shared__ float wse[4], wsd[4];
  if (lane == 0) { wse[wave] = se; wsd[wave] = sd; }
  __syncthreads();
  if (tid == 0) {
    float S = wse[0] + wse[1] + wse[2] + wse[3];
    float Dd = wsd[0] + wsd[1] + wsd[2] + wsd[3];
    out[row] = Dd / S + sc[0];
  }
}

extern "C" void kernel_launch(void* const* d_in, const int* in_sizes, int n_in,
                              void* d_out, int out_size, void* d_ws, size_t ws_size,
                              hipStream_t stream) {
  const float* x     = (const float*)d_in[0];
  const float* Wattn = (const float*)d_in[1];
  const float* battn = (const float*)d_in[2];
  const float* Wproj = (const float*)d_in[3];
  const float* bproj = (const float*)d_in[4];
  const float* Wfc   = (const float*)d_in[5];
  const float* bfc   = (const float*)d_in[6];
  float* out = (float*)d_out;

  // ws layout (bytes)
  const size_t OFF_XB     = 0;                         // bf16 [16384][1024]  33554432
  const size_t OFF_WQKB   = 33554432;                  // bf16 [2048][1024]    4194304
  const size_t OFF_QK     = 37748736;                  // bf16 [16384][2048]  67108864
  const size_t OFF_SCORES = 104857600;                 // f32  [8][2048][2048] 134217728
  const size_t OFF_VW     = 239075328;                 // f32  [16384]           65536
  const size_t OFF_WEFF   = 239140864;                 // f32  [1024]
  const size_t OFF_WVEFF  = 239144960;                 // f32  [1024]
  const size_t OFF_SC     = 239149056;                 // f32  [2] {c_eff, vb_eff}
  const size_t NEED       = 239149064;
  if (ws_size < NEED) return;

  char* ws = (char*)d_ws;
  ushort* xb    = (ushort*)(ws + OFF_XB);
  ushort* wqkb  = (ushort*)(ws + OFF_WQKB);
  ushort* qk    = (ushort*)(ws + OFF_QK);
  float* scores = (float*)(ws + OFF_SCORES);
  float* vw     = (float*)(ws + OFF_VW);
  float* w_eff  = (float*)(ws + OFF_WEFF);
  float* wv_eff = (float*)(ws + OFF_WVEFF);
  float* sc     = (float*)(ws + OFF_SC);

  cvt_kernel<<<dim3(4096), dim3(256), 0, stream>>>((const float4*)x, xb, (long)MTOT * D_EMB / 4);
  cvt_kernel<<<dim3(2048), dim3(256), 0, stream>>>((const float4*)Wattn, wqkb, (long)2048 * D_EMB / 4);

  zero_sc0<<<dim3(3), dim3(1024), 0, stream>>>(bproj, Wfc, bfc, w_eff, wv_eff, sc);
  prep1<<<dim3(4, 16), dim3(256), 0, stream>>>(Wproj, Wfc, w_eff);
  sc1_kernel<<<dim3(1), dim3(1024), 0, stream>>>(battn, w_eff, sc);
  prep2<<<dim3(4, 16), dim3(256), 0, stream>>>(Wattn, w_eff, wv_eff);
  vw_kernel<<<dim3(4096), dim3(256), 0, stream>>>(x, wv_eff, sc, vw);

  // GEMM1: qk[m, n] = x[m,:] . Wattn[n,:] + battn[n], n in [0,2048)
  gemm_nt<true><<<dim3(16, 128, 1), dim3(256), 0, stream>>>(
      xb, (long)D_EMB, 0L, wqkb, (long)D_EMB, 0L,
      (void*)qk, 2048L, 0L, battn, 1.0f, D_EMB);

  // GEMM2: scores[b, t, s] = (q[b,t,:] . k[b,s,:]) / 32
  gemm_nt<false><<<dim3(16, 16, NBATCH), dim3(256), 0, stream>>>(
      qk, 2048L, (long)SEQ * 2048, qk + 1024, 2048L, (long)SEQ * 2048,
      (void*)scores, (long)SEQ, (long)SEQ * SEQ, nullptr, 0.03125f, D_EMB);

  softmax_out<<<dim3(MTOT), dim3(256), 0, stream>>>(scores, vw, sc, out);
}

// Round 3
// 345.888 us; speedup vs baseline: 1.3344x; 1.0387x over previous
//
#include <hip/hip_runtime.h>
#include <stdint.h>

#define D_EMB 1024
#define NBATCH 8
#define SEQ 2048
#define MTOT (NBATCH*SEQ)   // 16384

typedef __attribute__((ext_vector_type(8))) short short8;
typedef __attribute__((ext_vector_type(4))) float f32x4;

__device__ __forceinline__ ushort bf16r(float x) {
  union { float f; uint32_t u; } c; c.f = x;
  return (ushort)((c.u + 0x7fffu + ((c.u >> 16) & 1u)) >> 16);
}
__device__ __forceinline__ float bf2f(ushort u) {
  union { uint32_t u; float f; } c; c.u = ((uint32_t)u) << 16; return c.f;
}

// async 16B/lane global->LDS (LDS dest must be wave-uniform base + lane*16)
__device__ __forceinline__ void cp16(const ushort* g, ushort* l) {
  __builtin_amdgcn_global_load_lds(
      (const __attribute__((address_space(1))) void*)g,
      (__attribute__((address_space(3))) void*)l, 16, 0, 0);
}

// ---------------- f32 -> bf16 convert (x4 vectorized) ----------------
__global__ void cvt_kernel(const float4* __restrict__ in, ushort* __restrict__ out, long n4) {
  long i = blockIdx.x * (long)blockDim.x + threadIdx.x;
  long stride = (long)gridDim.x * blockDim.x;
  for (; i < n4; i += stride) {
    float4 v = in[i];
    ushort4 o = make_ushort4(bf16r(v.x), bf16r(v.y), bf16r(v.z), bf16r(v.w));
    *(ushort4*)(out + i * 4) = o;
  }
}

// block 0: zero w_eff; block 1: zero wv_eff; block 2: sc[0] = sum_d bp[d]*Wfc[d] + bfc
__global__ void zero_sc0(const float* __restrict__ bp, const float* __restrict__ Wfc,
                         const float* __restrict__ bfc,
                         float* __restrict__ w_eff, float* __restrict__ wv_eff,
                         float* __restrict__ sc) {
  int tid = threadIdx.x;
  if (blockIdx.x == 0) { w_eff[tid] = 0.f; return; }
  if (blockIdx.x == 1) { wv_eff[tid] = 0.f; return; }
  float v = bp[tid] * Wfc[tid];
  int lane = tid & 63, w = tid >> 6;
  #pragma unroll
  for (int off = 32; off; off >>= 1) v += __shfl_xor(v, off);
  __shared__ float red[16];
  if (lane == 0) red[w] = v;
  __syncthreads();
  if (tid == 0) {
    float s = 0.f;
    #pragma unroll
    for (int i = 0; i < 16; i++) s += red[i];
    sc[0] = s + bfc[0];
  }
}

// w_eff[c] += sum over 64-d-chunk of Wfc[d]*Wp[d,c]   grid(4,16)
__global__ void prep1(const float* __restrict__ Wp, const float* __restrict__ Wfc,
                      float* __restrict__ w_eff) {
  int c = blockIdx.x * 256 + threadIdx.x;
  int d0 = blockIdx.y * 64;
  float s = 0.f;
  #pragma unroll 8
  for (int d = d0; d < d0 + 64; d++) s += Wfc[d] * Wp[(long)d * D_EMB + c];
  atomicAdd(&w_eff[c], s);
}

// sc[1] = vb_eff = sum_c battn[2048+c]*w_eff[c]   (after prep1)
__global__ void sc1_kernel(const float* __restrict__ battn, const float* __restrict__ w_eff,
                           float* __restrict__ sc) {
  int tid = threadIdx.x;
  float v = battn[2048 + tid] * w_eff[tid];
  int lane = tid & 63, w = tid >> 6;
  #pragma unroll
  for (int off = 32; off; off >>= 1) v += __shfl_xor(v, off);
  __shared__ float red[16];
  if (lane == 0) red[w] = v;
  __syncthreads();
  if (tid == 0) {
    float s = 0.f;
    #pragma unroll
    for (int i = 0; i < 16; i++) s += red[i];
    sc[1] = s;
  }
}

// wv_eff[d] += sum over 64-c-chunk of w_eff[c]*Wattn[2048+c, d]   grid(4,16)
__global__ void prep2(const float* __restrict__ Wattn, const float* __restrict__ w_eff,
                      float* __restrict__ wv_eff) {
  int d = blockIdx.x * 256 + threadIdx.x;
  int c0 = blockIdx.y * 64;
  float s = 0.f;
  #pragma unroll 8
  for (int c = c0; c < c0 + 64; c++) s += w_eff[c] * Wattn[(long)(2048 + c) * D_EMB + d];
  atomicAdd(&wv_eff[d], s);
}

// vw[m] = x[m,:] . wv_eff + vb_eff   (one wave per row, fp32)
__global__ void vw_kernel(const float* __restrict__ x, const float* __restrict__ wv_eff,
                          const float* __restrict__ sc, float* __restrict__ vw) {
  int wave = threadIdx.x >> 6, lane = threadIdx.x & 63;
  long m = (long)blockIdx.x * 4 + wave;
  const float* xr = x + m * D_EMB;
  float s = 0.f;
  #pragma unroll
  for (int i = 0; i < 16; i++) s += xr[i * 64 + lane] * wv_eff[i * 64 + lane];
  #pragma unroll
  for (int off = 32; off; off >>= 1) s += __shfl_xor(s, off);
  if (lane == 0) vw[m] = s + sc[1];
}

// ---------------- NT GEMM: C[m,n] = scale * sum_k A[m,k]*B[n,k] (+bias[n]) ----------------
// 128x128 tile, BK=32, 4 waves, each wave 64x64 (4x4 frags of 16x16x32 bf16 MFMA)
// staging via global_load_lds width=16; bank-conflict-free via fetch-side k-chunk swizzle:
//   LDS slot for (row, kc_global) is (row*4 + ((kc_global + ((row>>1)&3)) & 3)).
//   Write: LDS dest stays base + t*16 (required by global_load_lds); thread t fetches
//   the global chunk kc = ((t&3) - ((row0>>1)&3)) & 3 so data lands at its swizzled slot.
//   Read: frag (row, q) at slot (row*4 + ((q + ((row>>1)&3)) & 3)) -> bank starts cover
//   all 8 groups x 2 lanes = free 2-way (was 8-way, 8.4M conflict cycles/dispatch).
template<bool OUT_BF16>
__global__ __launch_bounds__(256) void gemm_nt(
    const ushort* __restrict__ A, long lda, long sAz,
    const ushort* __restrict__ B, long ldb, long sBz,
    void* __restrict__ Cv, long ldc, long sCz,
    const float* __restrict__ bias, float scale, int K) {
  __shared__ __align__(16) ushort lds_a[128 * 32];
  __shared__ __align__(16) ushort lds_b[128 * 32];
  int z = blockIdx.z;
  const ushort* Az = A + (long)z * sAz;
  const ushort* Bz = B + (long)z * sBz;
  long m0 = (long)blockIdx.y * 128, n0 = (long)blockIdx.x * 128;
  int t = threadIdx.x;
  int wave = t >> 6, lane = t & 63;
  int r = lane & 15, q = lane >> 4;
  int wm = (wave & 1) * 64, wn = (wave >> 1) * 64;

  f32x4 acc[4][4] = {};

  // staging with fetch-side swizzle
  int row0 = t >> 2;
  int kc = ((t & 3) - ((row0 >> 1) & 3)) & 3;   // global k-chunk this thread fetches
  const ushort* Ap0 = Az + (m0 + row0) * lda + kc * 8;
  const ushort* Ap1 = Az + (m0 + row0 + 64) * lda + kc * 8;  // (row0+64)>>1 & 3 == row0>>1 & 3
  const ushort* Bp0 = Bz + (n0 + row0) * ldb + kc * 8;
  const ushort* Bp1 = Bz + (n0 + row0 + 64) * ldb + kc * 8;

  // read-side swizzled slot offsets (in ushorts): frag (row, q)
  int swzr = (r >> 1) & 3;  // ((row>>1)&3) with row = 16*i + r etc. -> folds to (r>>1)&3

  #pragma unroll 1
  for (int k0 = 0; k0 < K; k0 += 32) {
    if (k0) __syncthreads();
    cp16(Ap0 + k0, lds_a + t * 8);
    cp16(Ap1 + k0, lds_a + (t + 256) * 8);
    cp16(Bp0 + k0, lds_b + t * 8);
    cp16(Bp1 + k0, lds_b + (t + 256) * 8);
    __syncthreads();
    short8 af[4], bf[4];
    int ks = ((q + swzr) & 3);
    #pragma unroll
    for (int i = 0; i < 4; i++)
      af[i] = *(const short8*)(lds_a + ((wm + i * 16 + r) * 4 + ks) * 8);
    #pragma unroll
    for (int j = 0; j < 4; j++)
      bf[j] = *(const short8*)(lds_b + ((wn + j * 16 + r) * 4 + ks) * 8);
    #pragma unroll
    for (int i = 0; i < 4; i++)
      #pragma unroll
      for (int j = 0; j < 4; j++)
        acc[i][j] = __builtin_amdgcn_mfma_f32_16x16x32_bf16(af[i], bf[j], acc[i][j], 0, 0, 0);
  }

  // epilogue: D row = wm+i*16+q*4+rr, col = wn+j*16+r  (verified C/D layout)
  #pragma unroll
  for (int i = 0; i < 4; i++) {
    #pragma unroll
    for (int j = 0; j < 4; j++) {
      long col = n0 + wn + j * 16 + r;
      float bj = (bias != nullptr) ? bias[col] : 0.f;
      #pragma unroll
      for (int rr = 0; rr < 4; rr++) {
        long row = m0 + wm + i * 16 + q * 4 + rr;
        float val = acc[i][j][rr] * scale + bj;
        if (OUT_BF16) ((ushort*)Cv)[(long)z * sCz + row * ldc + col] = bf16r(val);
        else          ((float*)Cv)[(long)z * sCz + row * ldc + col] = val;
      }
    }
  }
}

// softmax over s of bf16 scores[row, :] then dot with vw[b, :]; out = dot/sum + c_eff
__global__ __launch_bounds__(256) void softmax_out(
    const ushort* __restrict__ scores, const float* __restrict__ vw,
    const float* __restrict__ sc, float* __restrict__ out) {
  long row = blockIdx.x;
  int b = (int)(row >> 11);
  const ushort* srow = scores + row * SEQ;
  const float* vwr = vw + ((long)b << 11);
  int tid = threadIdx.x;
  int wave = tid >> 6, lane = tid & 63;
  // thread handles 8 contiguous cols: one uint4 (8 bf16)
  ushort4 raw0 = *(const ushort4*)(srow + tid * 8);
  ushort4 raw1 = *(const ushort4*)(srow + tid * 8 + 4);
  float vals[8] = { bf2f(raw0.x), bf2f(raw0.y), bf2f(raw0.z), bf2f(raw0.w),
                    bf2f(raw1.x), bf2f(raw1.y), bf2f(raw1.z), bf2f(raw1.w) };
  float mx = -1e30f;
  #pragma unroll
  for (int i = 0; i < 8; i++) mx = fmaxf(mx, vals[i]);
  #pragma unroll
  for (int off = 32; off; off >>= 1) mx = fmaxf(mx, __shfl_xor(mx, off));
  __shared__ float wmax[4];
  if (lane == 0) wmax[wave] = mx;
  __syncthreads();
  mx = fmaxf(fmaxf(wmax[0], wmax[1]), fmaxf(wmax[2], wmax[3]));
  float se = 0.f, sd = 0.f;
  #pragma unroll
  for (int i = 0; i < 8; i++) {
    float e = __expf(vals[i] - mx);
    se += e;
    sd += e * vwr[tid * 8 + i];
  }
  #pragma unroll
  for (int off = 32; off; off >>= 1) { se += __shfl_xor(se, off); sd += __shfl_xor(sd, off); }
  __shared__ float wse[4], wsd[4];
  if (lane == 0) { wse[wave] = se; wsd[wave] = sd; }
  __syncthreads();
  if (tid == 0) {
    float S = wse[0] + wse[1] + wse[2] + wse[3];
    float Dd = wsd[0] + wsd[1] + wsd[2] + wsd[3];
    out[row] = Dd / S + sc[0];
  }
}

extern "C" void kernel_launch(void* const* d_in, const int* in_sizes, int n_in,
                              void* d_out, int out_size, void* d_ws, size_t ws_size,
                              hipStream_t stream) {
  const float* x     = (const float*)d_in[0];
  const float* Wattn = (const float*)d_in[1];
  const float* battn = (const float*)d_in[2];
  const float* Wproj = (const float*)d_in[3];
  const float* bproj = (const float*)d_in[4];
  const float* Wfc   = (const float*)d_in[5];
  const float* bfc   = (const float*)d_in[6];
  float* out = (float*)d_out;

  // ws layout (bytes)
  const size_t OFF_XB     = 0;                         // bf16 [16384][1024]  33554432
  const size_t OFF_WQKB   = 33554432;                  // bf16 [2048][1024]    4194304
  const size_t OFF_QK     = 37748736;                  // bf16 [16384][2048]  67108864
  const size_t OFF_SCORES = 104857600;                 // bf16 [8][2048][2048] 67108864
  const size_t OFF_VW     = 239075328;                 // f32  [16384]           65536
  const size_t OFF_WEFF   = 239140864;                 // f32  [1024]
  const size_t OFF_WVEFF  = 239144960;                 // f32  [1024]
  const size_t OFF_SC     = 239149056;                 // f32  [2] {c_eff, vb_eff}
  const size_t NEED       = 239149064;
  if (ws_size < NEED) return;

  char* ws = (char*)d_ws;
  ushort* xb    = (ushort*)(ws + OFF_XB);
  ushort* wqkb  = (ushort*)(ws + OFF_WQKB);
  ushort* qk    = (ushort*)(ws + OFF_QK);
  ushort* scores= (ushort*)(ws + OFF_SCORES);
  float* vw     = (float*)(ws + OFF_VW);
  float* w_eff  = (float*)(ws + OFF_WEFF);
  float* wv_eff = (float*)(ws + OFF_WVEFF);
  float* sc     = (float*)(ws + OFF_SC);

  cvt_kernel<<<dim3(4096), dim3(256), 0, stream>>>((const float4*)x, xb, (long)MTOT * D_EMB / 4);
  cvt_kernel<<<dim3(2048), dim3(256), 0, stream>>>((const float4*)Wattn, wqkb, (long)2048 * D_EMB / 4);

  zero_sc0<<<dim3(3), dim3(1024), 0, stream>>>(bproj, Wfc, bfc, w_eff, wv_eff, sc);
  prep1<<<dim3(4, 16), dim3(256), 0, stream>>>(Wproj, Wfc, w_eff);
  sc1_kernel<<<dim3(1), dim3(1024), 0, stream>>>(battn, w_eff, sc);
  prep2<<<dim3(4, 16), dim3(256), 0, stream>>>(Wattn, w_eff, wv_eff);
  vw_kernel<<<dim3(4096), dim3(256), 0, stream>>>(x, wv_eff, sc, vw);

  // GEMM1: qk[m, n] = x[m,:] . Wattn[n,:] + battn[n], n in [0,2048)
  gemm_nt<true><<<dim3(16, 128, 1), dim3(256), 0, stream>>>(
      xb, (long)D_EMB, 0L, wqkb, (long)D_EMB, 0L,
      (void*)qk, 2048L, 0L, battn, 1.0f, D_EMB);

  // GEMM2: scores[b, t, s] = bf16( (q[b,t,:] . k[b,s,:]) / 32 )
  gemm_nt<true><<<dim3(16, 16, NBATCH), dim3(256), 0, stream>>>(
      qk, 2048L, (long)SEQ * 2048, qk + 1024, 2048L, (long)SEQ * 2048,
      (void*)scores, (long)SEQ, (long)SEQ * SEQ, nullptr, 0.03125f, D_EMB);

  softmax_out<<<dim3(MTOT), dim3(256), 0, stream>>>(scores, vw, sc, out);
}

// Round 4
// 307.606 us; speedup vs baseline: 1.5005x; 1.1244x over previous
//
#include <hip/hip_runtime.h>
#include <stdint.h>

#define D_EMB 1024
#define NBATCH 8
#define SEQ 2048
#define MTOT (NBATCH*SEQ)   // 16384

typedef __attribute__((ext_vector_type(8))) short short8;
typedef __attribute__((ext_vector_type(4))) float f32x4;

__device__ __forceinline__ ushort bf16r(float x) {
  union { float f; uint32_t u; } c; c.f = x;
  return (ushort)((c.u + 0x7fffu + ((c.u >> 16) & 1u)) >> 16);
}

// async 16B/lane global->LDS (LDS dest must be wave-uniform base + lane*16)
__device__ __forceinline__ void cp16(const ushort* g, ushort* l) {
  __builtin_amdgcn_global_load_lds(
      (const __attribute__((address_space(1))) void*)g,
      (__attribute__((address_space(3))) void*)l, 16, 0, 0);
}

// ---------------- f32 -> bf16 convert (x4 vectorized), for Wattn ----------------
__global__ void cvt_kernel(const float4* __restrict__ in, ushort* __restrict__ out, long n4) {
  long i = blockIdx.x * (long)blockDim.x + threadIdx.x;
  long stride = (long)gridDim.x * blockDim.x;
  for (; i < n4; i += stride) {
    float4 v = in[i];
    ushort4 o = make_ushort4(bf16r(v.x), bf16r(v.y), bf16r(v.z), bf16r(v.w));
    *(ushort4*)(out + i * 4) = o;
  }
}

// fused: convert one row of x to bf16 AND vw[row] = x[row,:].wv_eff + sc[1]
__global__ __launch_bounds__(256) void cvt_x_vw(
    const float4* __restrict__ x, const float4* __restrict__ wv_eff4,
    const float* __restrict__ sc, ushort* __restrict__ xb, float* __restrict__ vw) {
  long row = blockIdx.x;
  int tid = threadIdx.x;
  float4 v = x[row * 256 + tid];
  float4 w = wv_eff4[tid];
  ushort4 o = make_ushort4(bf16r(v.x), bf16r(v.y), bf16r(v.z), bf16r(v.w));
  *(ushort4*)(xb + row * D_EMB + tid * 4) = o;
  float s = v.x * w.x + v.y * w.y + v.z * w.z + v.w * w.w;
  int lane = tid & 63, wv0 = tid >> 6;
  #pragma unroll
  for (int off = 32; off; off >>= 1) s += __shfl_xor(s, off);
  __shared__ float red[4];
  if (lane == 0) red[wv0] = s;
  __syncthreads();
  if (tid == 0) vw[row] = red[0] + red[1] + red[2] + red[3] + sc[1];
}

// init: b0 zero w_eff, b1 zero wv_eff, b2 sc[0]=bp.Wfc+bfc, b3..34 zero num/den (32768 f32)
__global__ void init_kernel(const float* __restrict__ bp, const float* __restrict__ Wfc,
                            const float* __restrict__ bfc,
                            float* __restrict__ w_eff, float* __restrict__ wv_eff,
                            float* __restrict__ numden, float* __restrict__ sc) {
  int tid = threadIdx.x;
  int b = blockIdx.x;
  if (b == 0) { w_eff[tid] = 0.f; return; }
  if (b == 1) { wv_eff[tid] = 0.f; return; }
  if (b >= 3) { numden[(long)(b - 3) * 1024 + tid] = 0.f; return; }
  float v = bp[tid] * Wfc[tid];
  int lane = tid & 63, w = tid >> 6;
  #pragma unroll
  for (int off = 32; off; off >>= 1) v += __shfl_xor(v, off);
  __shared__ float red[16];
  if (lane == 0) red[w] = v;
  __syncthreads();
  if (tid == 0) {
    float s = 0.f;
    #pragma unroll
    for (int i = 0; i < 16; i++) s += red[i];
    sc[0] = s + bfc[0];
  }
}

// w_eff[c] += sum over 64-d-chunk of Wfc[d]*Wp[d,c]   grid(4,16)
__global__ void prep1(const float* __restrict__ Wp, const float* __restrict__ Wfc,
                      float* __restrict__ w_eff) {
  int c = blockIdx.x * 256 + threadIdx.x;
  int d0 = blockIdx.y * 64;
  float s = 0.f;
  #pragma unroll 8
  for (int d = d0; d < d0 + 64; d++) s += Wfc[d] * Wp[(long)d * D_EMB + c];
  atomicAdd(&w_eff[c], s);
}

// sc[1] = vb_eff = sum_c battn[2048+c]*w_eff[c]   (after prep1)
__global__ void sc1_kernel(const float* __restrict__ battn, const float* __restrict__ w_eff,
                           float* __restrict__ sc) {
  int tid = threadIdx.x;
  float v = battn[2048 + tid] * w_eff[tid];
  int lane = tid & 63, w = tid >> 6;
  #pragma unroll
  for (int off = 32; off; off >>= 1) v += __shfl_xor(v, off);
  __shared__ float red[16];
  if (lane == 0) red[w] = v;
  __syncthreads();
  if (tid == 0) {
    float s = 0.f;
    #pragma unroll
    for (int i = 0; i < 16; i++) s += red[i];
    sc[1] = s;
  }
}

// wv_eff[d] += sum over 64-c-chunk of w_eff[c]*Wattn[2048+c, d]   grid(4,16)
__global__ void prep2(const float* __restrict__ Wattn, const float* __restrict__ w_eff,
                      float* __restrict__ wv_eff) {
  int d = blockIdx.x * 256 + threadIdx.x;
  int c0 = blockIdx.y * 64;
  float s = 0.f;
  #pragma unroll 8
  for (int c = c0; c < c0 + 64; c++) s += w_eff[c] * Wattn[(long)(2048 + c) * D_EMB + d];
  atomicAdd(&wv_eff[d], s);
}

// ---------------- NT GEMM: 128x128 tile, BK=32, 16x16x32 bf16 MFMA ----------------
// FUSED=false: C[m,n] = bf16(scale*acc + bias[n])   (GEMM1 -> qk)
// FUSED=true : per-row partial softmax: num[m] += sum_n exp(scale*acc)*vw[n],
//              den[m] += sum_n exp(scale*acc)   (GEMM2; scores bounded, no max-sub needed)
// Conflict-free LDS via fetch-side k-chunk swizzle (see R3): slot(row,kc) = row*4 + ((kc+((row>>1)&3))&3)
template<bool FUSED>
__global__ __launch_bounds__(256, 3) void gemm_nt(
    const ushort* __restrict__ A, long lda, long sAz,
    const ushort* __restrict__ B, long ldb, long sBz,
    ushort* __restrict__ C, long ldc,
    const float* __restrict__ bias, float scale, int K,
    const float* __restrict__ vw, float* __restrict__ num, float* __restrict__ den) {
  __shared__ __align__(16) ushort lds_a[128 * 32];
  __shared__ __align__(16) ushort lds_b[128 * 32];
  int z = blockIdx.z;
  const ushort* Az = A + (long)z * sAz;
  const ushort* Bz = B + (long)z * sBz;
  long m0 = (long)blockIdx.y * 128, n0 = (long)blockIdx.x * 128;
  int t = threadIdx.x;
  int wave = t >> 6, lane = t & 63;
  int r = lane & 15, q = lane >> 4;
  int wm = (wave & 1) * 64, wn = (wave >> 1) * 64;

  f32x4 acc[4][4] = {};

  int row0 = t >> 2;
  int kc = ((t & 3) - ((row0 >> 1) & 3)) & 3;   // fetch-side swizzle
  const ushort* Ap0 = Az + (m0 + row0) * lda + kc * 8;
  const ushort* Ap1 = Az + (m0 + row0 + 64) * lda + kc * 8;
  const ushort* Bp0 = Bz + (n0 + row0) * ldb + kc * 8;
  const ushort* Bp1 = Bz + (n0 + row0 + 64) * ldb + kc * 8;

  int swzr = (r >> 1) & 3;

  #pragma unroll 1
  for (int k0 = 0; k0 < K; k0 += 32) {
    if (k0) __syncthreads();
    cp16(Ap0 + k0, lds_a + t * 8);
    cp16(Ap1 + k0, lds_a + (t + 256) * 8);
    cp16(Bp0 + k0, lds_b + t * 8);
    cp16(Bp1 + k0, lds_b + (t + 256) * 8);
    __syncthreads();
    short8 af[4], bf[4];
    int ks = ((q + swzr) & 3);
    #pragma unroll
    for (int i = 0; i < 4; i++)
      af[i] = *(const short8*)(lds_a + ((wm + i * 16 + r) * 4 + ks) * 8);
    #pragma unroll
    for (int j = 0; j < 4; j++)
      bf[j] = *(const short8*)(lds_b + ((wn + j * 16 + r) * 4 + ks) * 8);
    #pragma unroll
    for (int i = 0; i < 4; i++)
      #pragma unroll
      for (int j = 0; j < 4; j++)
        acc[i][j] = __builtin_amdgcn_mfma_f32_16x16x32_bf16(af[i], bf[j], acc[i][j], 0, 0, 0);
  }

  // C/D layout (verified): row = wm+i*16+q*4+rr, col = wn+j*16+r
  if (!FUSED) {
    #pragma unroll
    for (int i = 0; i < 4; i++) {
      #pragma unroll
      for (int j = 0; j < 4; j++) {
        long col = n0 + wn + j * 16 + r;
        float bj = bias[col];
        #pragma unroll
        for (int rr = 0; rr < 4; rr++) {
          long row = m0 + wm + i * 16 + q * 4 + rr;
          C[row * ldc + col] = bf16r(acc[i][j][rr] * scale + bj);
        }
      }
    }
  } else {
    const float* vwz = vw + (long)z * SEQ + n0;
    float* numz = num + (long)z * SEQ + m0;
    float* denz = den + (long)z * SEQ + m0;
    float vwj[4];
    #pragma unroll
    for (int j = 0; j < 4; j++) vwj[j] = vwz[wn + j * 16 + r];
    #pragma unroll
    for (int i = 0; i < 4; i++) {
      #pragma unroll
      for (int rr = 0; rr < 4; rr++) {
        float sn = 0.f, sd = 0.f;
        #pragma unroll
        for (int j = 0; j < 4; j++) {
          float e = __expf(acc[i][j][rr] * scale);
          sd += e;
          sn += e * vwj[j];
        }
        #pragma unroll
        for (int off = 1; off < 16; off <<= 1) {
          sn += __shfl_xor(sn, off);
          sd += __shfl_xor(sd, off);
        }
        if (r == 0) {
          int row = wm + i * 16 + q * 4 + rr;
          atomicAdd(&numz[row], sn);
          atomicAdd(&denz[row], sd);
        }
      }
    }
  }
}

// out[row] = num[row]/den[row] + c_eff
__global__ __launch_bounds__(256) void finalize(
    const float* __restrict__ num, const float* __restrict__ den,
    const float* __restrict__ sc, float* __restrict__ out) {
  long i = blockIdx.x * 256L + threadIdx.x;
  out[i] = num[i] / den[i] + sc[0];
}

extern "C" void kernel_launch(void* const* d_in, const int* in_sizes, int n_in,
                              void* d_out, int out_size, void* d_ws, size_t ws_size,
                              hipStream_t stream) {
  const float* x     = (const float*)d_in[0];
  const float* Wattn = (const float*)d_in[1];
  const float* battn = (const float*)d_in[2];
  const float* Wproj = (const float*)d_in[3];
  const float* bproj = (const float*)d_in[4];
  const float* Wfc   = (const float*)d_in[5];
  const float* bfc   = (const float*)d_in[6];
  float* out = (float*)d_out;

  // ws layout (bytes)
  const size_t OFF_XB    = 0;          // bf16 [16384][1024]  33554432
  const size_t OFF_WQKB  = 33554432;   // bf16 [2048][1024]    4194304
  const size_t OFF_QK    = 37748736;   // bf16 [16384][2048]  67108864
  const size_t OFF_NUM   = 104857600;  // f32  [16384]           65536
  const size_t OFF_DEN   = 104923136;  // f32  [16384]           65536
  const size_t OFF_VW    = 104988672;  // f32  [16384]           65536
  const size_t OFF_WEFF  = 105054208;  // f32  [1024]
  const size_t OFF_WVEFF = 105058304;  // f32  [1024]
  const size_t OFF_SC    = 105062400;  // f32  [2] {c_eff, vb_eff}
  const size_t NEED      = 105062408;
  if (ws_size < NEED) return;

  char* ws = (char*)d_ws;
  ushort* xb    = (ushort*)(ws + OFF_XB);
  ushort* wqkb  = (ushort*)(ws + OFF_WQKB);
  ushort* qk    = (ushort*)(ws + OFF_QK);
  float* num    = (float*)(ws + OFF_NUM);
  float* den    = (float*)(ws + OFF_DEN);
  float* vw     = (float*)(ws + OFF_VW);
  float* w_eff  = (float*)(ws + OFF_WEFF);
  float* wv_eff = (float*)(ws + OFF_WVEFF);
  float* sc     = (float*)(ws + OFF_SC);

  // num/den are contiguous: zero both via one pointer
  init_kernel<<<dim3(35), dim3(1024), 0, stream>>>(bproj, Wfc, bfc, w_eff, wv_eff, num, sc);
  prep1<<<dim3(4, 16), dim3(256), 0, stream>>>(Wproj, Wfc, w_eff);
  sc1_kernel<<<dim3(1), dim3(1024), 0, stream>>>(battn, w_eff, sc);
  prep2<<<dim3(4, 16), dim3(256), 0, stream>>>(Wattn, w_eff, wv_eff);

  cvt_kernel<<<dim3(2048), dim3(256), 0, stream>>>((const float4*)Wattn, wqkb, (long)2048 * D_EMB / 4);
  cvt_x_vw<<<dim3(MTOT), dim3(256), 0, stream>>>((const float4*)x, (const float4*)wv_eff, sc, xb, vw);

  // GEMM1: qk[m, n] = bf16( x[m,:] . Wattn[n,:] + battn[n] ), n in [0,2048)
  gemm_nt<false><<<dim3(16, 128, 1), dim3(256), 0, stream>>>(
      xb, (long)D_EMB, 0L, wqkb, (long)D_EMB, 0L,
      qk, 2048L, battn, 1.0f, D_EMB, nullptr, nullptr, nullptr);

  // GEMM2 fused: num/den partial softmax sums per row (scale = 1/sqrt(1024))
  gemm_nt<true><<<dim3(16, 16, NBATCH), dim3(256), 0, stream>>>(
      qk, 2048L, (long)SEQ * 2048, qk + 1024, 2048L, (long)SEQ * 2048,
      nullptr, 0L, nullptr, 0.03125f, D_EMB, vw, num, den);

  finalize<<<dim3(64), dim3(256), 0, stream>>>(num, den, sc, out);
}

// Round 5
// 271.330 us; speedup vs baseline: 1.7011x; 1.1337x over previous
//
#include <hip/hip_runtime.h>
#include <stdint.h>

#define D_EMB 1024
#define NBATCH 8
#define SEQ 2048
#define MTOT (NBATCH*SEQ)   // 16384

typedef __attribute__((ext_vector_type(8))) short short8;
typedef __attribute__((ext_vector_type(4))) float f32x4;

__device__ __forceinline__ ushort bf16r(float x) {
  union { float f; uint32_t u; } c; c.f = x;
  return (ushort)((c.u + 0x7fffu + ((c.u >> 16) & 1u)) >> 16);
}

// async 16B/lane global->LDS (LDS dest must be wave-uniform base + lane*16)
__device__ __forceinline__ void cp16(const ushort* g, ushort* l) {
  __builtin_amdgcn_global_load_lds(
      (const __attribute__((address_space(1))) void*)g,
      (__attribute__((address_space(3))) void*)l, 16, 0, 0);
}

// ---------------- f32 -> bf16 convert (x4 vectorized), for Wattn ----------------
__global__ void cvt_kernel(const float4* __restrict__ in, ushort* __restrict__ out, long n4) {
  long i = blockIdx.x * (long)blockDim.x + threadIdx.x;
  long stride = (long)gridDim.x * blockDim.x;
  for (; i < n4; i += stride) {
    float4 v = in[i];
    ushort4 o = make_ushort4(bf16r(v.x), bf16r(v.y), bf16r(v.z), bf16r(v.w));
    *(ushort4*)(out + i * 4) = o;
  }
}

// fused: wave-per-row; convert x row to bf16 AND vw[row] = x[row,:].wv_eff + sc[1]
// no LDS / no block barrier — pure wave shuffle reduce
__global__ __launch_bounds__(256) void cvt_x_vw(
    const float4* __restrict__ x4, const float4* __restrict__ wv4,
    const float* __restrict__ sc, ushort* __restrict__ xb, float* __restrict__ vw) {
  int wave = threadIdx.x >> 6, lane = threadIdx.x & 63;
  long row = (long)blockIdx.x * 4 + wave;
  const float4* xr = x4 + row * 256;
  ushort* xo = xb + row * D_EMB;
  float s = 0.f;
  #pragma unroll
  for (int i = 0; i < 4; i++) {
    int idx = lane + i * 64;
    float4 v = xr[idx];
    float4 w = wv4[idx];
    *(ushort4*)(xo + idx * 4) = make_ushort4(bf16r(v.x), bf16r(v.y), bf16r(v.z), bf16r(v.w));
    s += v.x * w.x + v.y * w.y + v.z * w.z + v.w * w.w;
  }
  #pragma unroll
  for (int off = 32; off; off >>= 1) s += __shfl_xor(s, off);
  if (lane == 0) vw[row] = s + sc[1];
}

// init: b0 zero w_eff, b1 zero wv_eff, b2 sc[0]=bp.Wfc+bfc, b3..34 zero num/den (32768 f32)
__global__ void init_kernel(const float* __restrict__ bp, const float* __restrict__ Wfc,
                            const float* __restrict__ bfc,
                            float* __restrict__ w_eff, float* __restrict__ wv_eff,
                            float* __restrict__ numden, float* __restrict__ sc) {
  int tid = threadIdx.x;
  int b = blockIdx.x;
  if (b == 0) { w_eff[tid] = 0.f; return; }
  if (b == 1) { wv_eff[tid] = 0.f; return; }
  if (b >= 3) { numden[(long)(b - 3) * 1024 + tid] = 0.f; return; }
  float v = bp[tid] * Wfc[tid];
  int lane = tid & 63, w = tid >> 6;
  #pragma unroll
  for (int off = 32; off; off >>= 1) v += __shfl_xor(v, off);
  __shared__ float red[16];
  if (lane == 0) red[w] = v;
  __syncthreads();
  if (tid == 0) {
    float s = 0.f;
    #pragma unroll
    for (int i = 0; i < 16; i++) s += red[i];
    sc[0] = s + bfc[0];
  }
}

// w_eff[c] += sum over 16-d-chunk of Wfc[d]*Wp[d,c]   grid(4,64)
__global__ void prep1(const float* __restrict__ Wp, const float* __restrict__ Wfc,
                      float* __restrict__ w_eff) {
  int c = blockIdx.x * 256 + threadIdx.x;
  int d0 = blockIdx.y * 16;
  float s = 0.f;
  #pragma unroll
  for (int d = d0; d < d0 + 16; d++) s += Wfc[d] * Wp[(long)d * D_EMB + c];
  atomicAdd(&w_eff[c], s);
}

// grid(4,65): by<64 -> wv_eff[d] += sum over 16-c-chunk of w_eff[c]*Wattn[2048+c, d]
//             by==64 (bx==0) -> sc[1] = sum_c battn[2048+c]*w_eff[c]
__global__ void prep2(const float* __restrict__ Wattn, const float* __restrict__ battn,
                      const float* __restrict__ w_eff, float* __restrict__ wv_eff,
                      float* __restrict__ sc) {
  int tid = threadIdx.x;
  if (blockIdx.y == 64) {
    if (blockIdx.x != 0) return;
    float v = 0.f;
    #pragma unroll
    for (int i = 0; i < 4; i++) { int c = tid + i * 256; v += battn[2048 + c] * w_eff[c]; }
    int lane = tid & 63, w = tid >> 6;
    #pragma unroll
    for (int off = 32; off; off >>= 1) v += __shfl_xor(v, off);
    __shared__ float red[4];
    if (lane == 0) red[w] = v;
    __syncthreads();
    if (tid == 0) sc[1] = red[0] + red[1] + red[2] + red[3];
    return;
  }
  int d = blockIdx.x * 256 + tid;
  int c0 = blockIdx.y * 16;
  float s = 0.f;
  #pragma unroll
  for (int c = c0; c < c0 + 16; c++) s += w_eff[c] * Wattn[(long)(2048 + c) * D_EMB + d];
  atomicAdd(&wv_eff[d], s);
}

// ---------------- NT GEMM: 128x128 tile, BK=64, 16x16x32 bf16 MFMA ----------------
// FUSED=false: C[m,n] = bf16(scale*acc + bias[n])   (GEMM1 -> qk)
// FUSED=true : per-row partial softmax: num[m] += sum_n exp(scale*acc)*vw[n], den[m] += sum_n exp
// LDS: [128 rows][8 chunks of 16B], XOR swizzle chunk_stored = chunk ^ (row&7):
//   write: global_load_lds dest = base + t*16 (slot s: row=s>>3, slotchunk=s&7);
//          thread fetches global chunk kc = (t&7) ^ ((t>>3)&7)  (row&7 invariant across +32j)
//   read:  frag(row, kk, q) at slot row*8 + ((kk*4+q) ^ (r&7)) -> 2 lanes/bank-group = free
template<bool FUSED>
__global__ __launch_bounds__(256, 4) void gemm_nt(
    const ushort* __restrict__ A, long lda, long sAz,
    const ushort* __restrict__ B, long ldb, long sBz,
    ushort* __restrict__ C, long ldc,
    const float* __restrict__ bias, float scale, int K,
    const float* __restrict__ vw, float* __restrict__ num, float* __restrict__ den) {
  __shared__ __align__(16) ushort lds_a[128 * 64];
  __shared__ __align__(16) ushort lds_b[128 * 64];
  int z = blockIdx.z;
  const ushort* Az = A + (long)z * sAz;
  const ushort* Bz = B + (long)z * sBz;
  long m0 = (long)blockIdx.y * 128, n0 = (long)blockIdx.x * 128;
  int t = threadIdx.x;
  int wave = t >> 6, lane = t & 63;
  int r = lane & 15, q = lane >> 4;
  int wm = (wave & 1) * 64, wn = (wave >> 1) * 64;

  f32x4 acc[4][4] = {};

  // staging: thread owns slots t, t+256, t+512, t+768 -> rows r0, r0+32, r0+64, r0+96
  int row0 = t >> 3;
  int kc = (t & 7) ^ (row0 & 7);
  const ushort* Ap = Az + (m0 + row0) * lda + kc * 8;
  const ushort* Bp = Bz + (n0 + row0) * ldb + kc * 8;
  long a32 = 32 * lda, b32 = 32 * ldb;

  int swz = r & 7;

  #pragma unroll 1
  for (int k0 = 0; k0 < K; k0 += 64) {
    if (k0) __syncthreads();
    cp16(Ap + k0,            lds_a + t * 8);
    cp16(Ap + k0 + a32,      lds_a + (t + 256) * 8);
    cp16(Ap + k0 + 2 * a32,  lds_a + (t + 512) * 8);
    cp16(Ap + k0 + 3 * a32,  lds_a + (t + 768) * 8);
    cp16(Bp + k0,            lds_b + t * 8);
    cp16(Bp + k0 + b32,      lds_b + (t + 256) * 8);
    cp16(Bp + k0 + 2 * b32,  lds_b + (t + 512) * 8);
    cp16(Bp + k0 + 3 * b32,  lds_b + (t + 768) * 8);
    __syncthreads();
    #pragma unroll
    for (int kk = 0; kk < 2; kk++) {
      int cidx = (kk * 4 + q) ^ swz;
      short8 af[4], bf[4];
      #pragma unroll
      for (int i = 0; i < 4; i++)
        af[i] = *(const short8*)(lds_a + ((wm + i * 16 + r) * 8 + cidx) * 8);
      #pragma unroll
      for (int j = 0; j < 4; j++)
        bf[j] = *(const short8*)(lds_b + ((wn + j * 16 + r) * 8 + cidx) * 8);
      #pragma unroll
      for (int i = 0; i < 4; i++)
        #pragma unroll
        for (int j = 0; j < 4; j++)
          acc[i][j] = __builtin_amdgcn_mfma_f32_16x16x32_bf16(af[i], bf[j], acc[i][j], 0, 0, 0);
    }
  }

  // C/D layout (verified): row = wm+i*16+q*4+rr, col = wn+j*16+r
  if (!FUSED) {
    #pragma unroll
    for (int i = 0; i < 4; i++) {
      #pragma unroll
      for (int j = 0; j < 4; j++) {
        long col = n0 + wn + j * 16 + r;
        float bj = bias[col];
        #pragma unroll
        for (int rr = 0; rr < 4; rr++) {
          long row = m0 + wm + i * 16 + q * 4 + rr;
          C[row * ldc + col] = bf16r(acc[i][j][rr] * scale + bj);
        }
      }
    }
  } else {
    const float* vwz = vw + (long)z * SEQ + n0;
    float* numz = num + (long)z * SEQ + m0;
    float* denz = den + (long)z * SEQ + m0;
    float vwj[4];
    #pragma unroll
    for (int j = 0; j < 4; j++) vwj[j] = vwz[wn + j * 16 + r];
    #pragma unroll
    for (int i = 0; i < 4; i++) {
      #pragma unroll
      for (int rr = 0; rr < 4; rr++) {
        float sn = 0.f, sd = 0.f;
        #pragma unroll
        for (int j = 0; j < 4; j++) {
          float e = __expf(acc[i][j][rr] * scale);
          sd += e;
          sn += e * vwj[j];
        }
        #pragma unroll
        for (int off = 1; off < 16; off <<= 1) {
          sn += __shfl_xor(sn, off);
          sd += __shfl_xor(sd, off);
        }
        if (r == 0) {
          int row = wm + i * 16 + q * 4 + rr;
          atomicAdd(&numz[row], sn);
          atomicAdd(&denz[row], sd);
        }
      }
    }
  }
}

// out[row] = num[row]/den[row] + c_eff
__global__ __launch_bounds__(256) void finalize(
    const float* __restrict__ num, const float* __restrict__ den,
    const float* __restrict__ sc, float* __restrict__ out) {
  long i = blockIdx.x * 256L + threadIdx.x;
  out[i] = num[i] / den[i] + sc[0];
}

extern "C" void kernel_launch(void* const* d_in, const int* in_sizes, int n_in,
                              void* d_out, int out_size, void* d_ws, size_t ws_size,
                              hipStream_t stream) {
  const float* x     = (const float*)d_in[0];
  const float* Wattn = (const float*)d_in[1];
  const float* battn = (const float*)d_in[2];
  const float* Wproj = (const float*)d_in[3];
  const float* bproj = (const float*)d_in[4];
  const float* Wfc   = (const float*)d_in[5];
  const float* bfc   = (const float*)d_in[6];
  float* out = (float*)d_out;

  // ws layout (bytes)
  const size_t OFF_XB    = 0;          // bf16 [16384][1024]  33554432
  const size_t OFF_WQKB  = 33554432;   // bf16 [2048][1024]    4194304
  const size_t OFF_QK    = 37748736;   // bf16 [16384][2048]  67108864
  const size_t OFF_NUM   = 104857600;  // f32  [16384]           65536
  const size_t OFF_DEN   = 104923136;  // f32  [16384]           65536
  const size_t OFF_VW    = 104988672;  // f32  [16384]           65536
  const size_t OFF_WEFF  = 105054208;  // f32  [1024]
  const size_t OFF_WVEFF = 105058304;  // f32  [1024]
  const size_t OFF_SC    = 105062400;  // f32  [2] {c_eff, vb_eff}
  const size_t NEED      = 105062408;
  if (ws_size < NEED) return;

  char* ws = (char*)d_ws;
  ushort* xb    = (ushort*)(ws + OFF_XB);
  ushort* wqkb  = (ushort*)(ws + OFF_WQKB);
  ushort* qk    = (ushort*)(ws + OFF_QK);
  float* num    = (float*)(ws + OFF_NUM);
  float* den    = (float*)(ws + OFF_DEN);
  float* vw     = (float*)(ws + OFF_VW);
  float* w_eff  = (float*)(ws + OFF_WEFF);
  float* wv_eff = (float*)(ws + OFF_WVEFF);
  float* sc     = (float*)(ws + OFF_SC);

  init_kernel<<<dim3(35), dim3(1024), 0, stream>>>(bproj, Wfc, bfc, w_eff, wv_eff, num, sc);
  prep1<<<dim3(4, 64), dim3(256), 0, stream>>>(Wproj, Wfc, w_eff);
  prep2<<<dim3(4, 65), dim3(256), 0, stream>>>(Wattn, battn, w_eff, wv_eff, sc);

  cvt_kernel<<<dim3(2048), dim3(256), 0, stream>>>((const float4*)Wattn, wqkb, (long)2048 * D_EMB / 4);
  cvt_x_vw<<<dim3(4096), dim3(256), 0, stream>>>((const float4*)x, (const float4*)wv_eff, sc, xb, vw);

  // GEMM1: qk[m, n] = bf16( x[m,:] . Wattn[n,:] + battn[n] ), n in [0,2048)
  gemm_nt<false><<<dim3(16, 128, 1), dim3(256), 0, stream>>>(
      xb, (long)D_EMB, 0L, wqkb, (long)D_EMB, 0L,
      qk, 2048L, battn, 1.0f, D_EMB, nullptr, nullptr, nullptr);

  // GEMM2 fused: num/den partial softmax sums per row (scale = 1/sqrt(1024))
  gemm_nt<true><<<dim3(16, 16, NBATCH), dim3(256), 0, stream>>>(
      qk, 2048L, (long)SEQ * 2048, qk + 1024, 2048L, (long)SEQ * 2048,
      nullptr, 0L, nullptr, 0.03125f, D_EMB, vw, num, den);

  finalize<<<dim3(64), dim3(256), 0, stream>>>(num, den, sc, out);
}